// Round 8
// baseline (141.871 us; speedup 1.0000x reference)
//
#include <hip/hip_runtime.h>
#include <hip/hip_bf16.h>

#define B 8
#define N 1024
#define IN 256
#define H 4
#define D 64
#define O 256   // H*D
#define BN (B*N)

typedef __attribute__((ext_vector_type(4))) float f32x4;
typedef __attribute__((ext_vector_type(8))) short short8;
typedef __attribute__((ext_vector_type(4))) short short4v;

__device__ __forceinline__ short f2bf(float f){
  __hip_bfloat16 b = __float2bfloat16(f);
  return __builtin_bit_cast(short, b);
}

// ---------------------------------------------------------------------------
// k_fused: blocks [0,1024) pack adj int32 -> bitmask (BW-bound, 134MB);
//          blocks [1024,1536) compute Wh = h @ W^T with inline fp32->bf16 cvt,
//          writing VT[b][h][d][n] bf16 + fused src/dst epilogue.
// GEMM MFMA/VALU work co-schedules under the pack blocks' HBM stalls.
// (R6 retry with ONLY this variable changed vs R5 — k_attn and ws layout
//  are byte-identical to the passing R5 version.)
// ---------------------------------------------------------------------------
#define PACK_BLOCKS 1024
__global__ __launch_bounds__(256) void k_fused(const int* __restrict__ adj,
                                               unsigned* __restrict__ bits,
                                               const float* __restrict__ hmat,
                                               const float* __restrict__ Wmat,
                                               const float* __restrict__ avec,
                                               short* __restrict__ VT,
                                               float* __restrict__ src,
                                               float* __restrict__ dst){
  if(blockIdx.x < PACK_BLOCKS){
    // ---- mask pack: thread t handles 32 consecutive ints -> 1 bit-word
    int t = blockIdx.x * 256 + threadIdx.x;          // [0, 262144)
    const int4* p = (const int4*)(adj + ((size_t)t << 5));
    unsigned word = 0;
    #pragma unroll
    for(int k = 0; k < 8; k++){
      int4 m = p[k];
      word |= (m.x != 0 ? 1u : 0u) << (k*4 + 0);
      word |= (m.y != 0 ? 1u : 0u) << (k*4 + 1);
      word |= (m.z != 0 ? 1u : 0u) << (k*4 + 2);
      word |= (m.w != 0 ? 1u : 0u) << (k*4 + 3);
    }
    bits[t] = word;
    return;
  }
  // ---- Wh GEMM: m-tile 16 per block, wave = head
  const int t = threadIdx.x;
  const int hh = t >> 6, lane = t & 63, quad = lane >> 4, l16 = lane & 15;
  const int mbase = (blockIdx.x - PACK_BLOCKS) * 16;
  f32x4 acc[4];
  #pragma unroll
  for(int x=0;x<4;x++) acc[x] = (f32x4){0.f,0.f,0.f,0.f};
  const float* ap  = hmat + (size_t)(mbase + l16) * IN + quad * 8;
  const float* bp0 = Wmat + (size_t)(hh * 64 + l16) * IN + quad * 8;
  #pragma unroll
  for(int kk = 0; kk < 8; kk++){
    const int k0 = kk * 32;
    float4 a0 = *(const float4*)(ap + k0);
    float4 a1 = *(const float4*)(ap + k0 + 4);
    short8 A;
    A[0]=f2bf(a0.x); A[1]=f2bf(a0.y); A[2]=f2bf(a0.z); A[3]=f2bf(a0.w);
    A[4]=f2bf(a1.x); A[5]=f2bf(a1.y); A[6]=f2bf(a1.z); A[7]=f2bf(a1.w);
    #pragma unroll
    for(int dt=0; dt<4; dt++){
      const float* bp = bp0 + (size_t)dt*16*IN + k0;
      float4 b0 = *(const float4*)bp;
      float4 b1 = *(const float4*)(bp + 4);
      short8 Bf;
      Bf[0]=f2bf(b0.x); Bf[1]=f2bf(b0.y); Bf[2]=f2bf(b0.z); Bf[3]=f2bf(b0.w);
      Bf[4]=f2bf(b1.x); Bf[5]=f2bf(b1.y); Bf[6]=f2bf(b1.z); Bf[7]=f2bf(b1.w);
      acc[dt] = __builtin_amdgcn_mfma_f32_16x16x32_bf16(A, Bf, acc[dt], 0, 0, 0);
    }
  }
  // epilogue 1: bf16 VT store.  C row = quad*4+r -> token n, col l16 -> d.
  const int bb = mbase >> 10;
  const int nb = (mbase & (N-1)) + quad * 4;
  const int bh = bb * H + hh;
  #pragma unroll
  for(int dt=0; dt<4; dt++){
    int d = dt*16 + l16;
    short4v pk;
    pk[0]=f2bf(acc[dt][0]); pk[1]=f2bf(acc[dt][1]);
    pk[2]=f2bf(acc[dt][2]); pk[3]=f2bf(acc[dt][3]);
    *(short4v*)(VT + (((size_t)bh * D + d) << 10) + nb) = pk;
  }
  // epilogue 2: fused src/dst (fp32 acc dot a-halves, shfl-reduce over l16)
  float as[4], ad[4];
  #pragma unroll
  for(int dt=0; dt<4; dt++){
    as[dt] = avec[hh*(2*D) + dt*16 + l16];
    ad[dt] = avec[hh*(2*D) + D + dt*16 + l16];
  }
  #pragma unroll
  for(int r=0; r<4; r++){
    float s = 0.f, dd = 0.f;
    #pragma unroll
    for(int dt=0; dt<4; dt++){ s += acc[dt][r]*as[dt]; dd += acc[dt][r]*ad[dt]; }
    #pragma unroll
    for(int off=1; off<16; off<<=1){
      s  += __shfl_xor(s, off, 64);
      dd += __shfl_xor(dd, off, 64);
    }
    if(l16 == 0){
      int n = nb + r;
      src[(size_t)bh * N + n] = s;
      dst[(size_t)bh * N + n] = dd;
    }
  }
}

// ---------------------------------------------------------------------------
// k_attn: full-j masked-softmax + PV, software-pipelined (depth 2) B-fragment
// prefetch from global VT. Row-sums accumulated by an extra MFMA against a
// ones-fragment (no shuffle reduction, no VALU lsum chain).
// grid dim3(16, H, B) x 256; one barrier total.  [byte-identical to R5]
// ---------------------------------------------------------------------------
__global__ __launch_bounds__(256, 4) void k_attn(const short* __restrict__ VT,
                                              const float* __restrict__ src,
                                              const float* __restrict__ dst,
                                              const unsigned* __restrict__ bits,
                                              float* __restrict__ out){
  __shared__ float dsh[N];
  const int t = threadIdx.x;
  const int wave = t >> 6, lane = t & 63, quad = lane >> 4, l16 = lane & 15;
  const int b = blockIdx.z, hh = blockIdx.y;
  const int bh = b * H + hh;
  const int i0 = blockIdx.x * 64;
  #pragma unroll
  for(int j = t; j < N; j += 256) dsh[j] = dst[(size_t)bh * N + j];
  const int i = i0 + wave * 16 + l16;
  const float si = src[(size_t)bh * N + i];
  // preload this row's full 1024 mask bits (32 words, 8 x int4)
  const int4* mp = (const int4*)(bits + ((size_t)b * N + i) * 32);
  int4 mv[8];
  #pragma unroll
  for(int k=0;k<8;k++) mv[k] = mp[k];
  const unsigned* mw = (const unsigned*)mv;
  const short* vrow = VT + (((size_t)bh * D) << 10) + quad * 8;
  // ones B-fragment (bf16 1.0 = 0x3F80) for row-sum accumulation
  short8 ones;
  #pragma unroll
  for(int k=0;k<8;k++) ones[k] = (short)0x3F80;
  f32x4 acc[4], accl;
  #pragma unroll
  for(int x=0;x<4;x++) acc[x] = (f32x4){0.f,0.f,0.f,0.f};
  accl = (f32x4){0.f,0.f,0.f,0.f};
  // 3 rotating register buffers for B-fragments (depth-2 prefetch)
  short8 buf[3][4];
  #pragma unroll
  for(int pre=0; pre<2; pre++)
    #pragma unroll
    for(int dt=0; dt<4; dt++)
      buf[pre][dt] = *(const short8*)(vrow + (((size_t)(dt*16 + l16)) << 10) + pre*32);
  __syncthreads();
  #pragma unroll
  for(int jt = 0; jt < 32; jt++){
    const int cur = jt % 3, nxt = (jt + 2) % 3;
    if(jt + 2 < 32){
      #pragma unroll
      for(int dt=0; dt<4; dt++)
        buf[nxt][dt] = *(const short8*)(vrow + (((size_t)(dt*16 + l16)) << 10) + (jt+2)*32);
    }
    const int j0 = jt * 32;
    const unsigned word = mw[jt];
    float4 d0 = *(const float4*)&dsh[j0 + quad*8];
    float4 d1 = *(const float4*)&dsh[j0 + quad*8 + 4];
    float dv[8] = {d0.x,d0.y,d0.z,d0.w,d1.x,d1.y,d1.z,d1.w};
    short8 P;
    #pragma unroll
    for(int jj=0; jj<8; jj++){
      float e = si + dv[jj];
      e = fmaxf(e, 0.2f * e);                          // leaky_relu(0.2)
      float p = ((word >> (quad*8 + jj)) & 1u) ? __expf(e) : 0.f;
      P[jj] = f2bf(p);
    }
    accl = __builtin_amdgcn_mfma_f32_16x16x32_bf16(P, ones, accl, 0, 0, 0);
    #pragma unroll
    for(int dt=0; dt<4; dt++)
      acc[dt] = __builtin_amdgcn_mfma_f32_16x16x32_bf16(P, buf[cur][dt], acc[dt], 0, 0, 0);
  }
  // epilogue: C row = quad*4+r, col = l16. accl[r] holds that row's sum
  // (identical across cols) -> denominator is already lane-local.
  #pragma unroll
  for(int r=0; r<4; r++){
    float inv = 1.0f / accl[r];
    int ig = i0 + wave*16 + quad*4 + r;
    float* op = out + ((size_t)b * N + ig) * O + hh * D + l16;
    #pragma unroll
    for(int dt=0; dt<4; dt++) op[dt*16] = acc[dt][r] * inv;
  }
}

extern "C" void kernel_launch(void* const* d_in, const int* in_sizes, int n_in,
                              void* d_out, int out_size, void* d_ws, size_t ws_size,
                              hipStream_t stream) {
  const float* hmat = (const float*)d_in[0];
  const float* Wmat = (const float*)d_in[1];
  const float* avec = (const float*)d_in[2];
  const int* adj    = (const int*)d_in[3];   // numpy bool -> int32 per harness
  float* out = (float*)d_out;
  char* ws = (char*)d_ws;
  // ws layout byte-identical to R5 (hbf/wbf slots at 4MB/8MB now unused)
  short*    VT    = (short*)   (ws);                         //  4 MB
  unsigned* bits  = (unsigned*)(ws + (size_t) 9*1024*1024);  //  1 MB
  float*    src   = (float*)   (ws + (size_t)10*1024*1024);  //  128 KB
  float*    dst   = (float*)   (ws + (size_t)10*1024*1024 + 131072);
  k_fused<<<PACK_BLOCKS + BN/16, 256, 0, stream>>>(adj, bits, hmat, Wmat, avec, VT, src, dst);
  k_attn<<<dim3(16, H, B), 256, 0, stream>>>(VT, src, dst, bits, out);
}

// Round 9
// 129.821 us; speedup vs baseline: 1.0928x; 1.0928x over previous
//
#include <hip/hip_runtime.h>
#include <hip/hip_bf16.h>

#define B 8
#define N 1024
#define IN 256
#define H 4
#define D 64
#define O 256   // H*D
#define BN (B*N)

typedef __attribute__((ext_vector_type(4))) float f32x4;
typedef __attribute__((ext_vector_type(8))) short short8;
typedef __attribute__((ext_vector_type(4))) short short4v;

__device__ __forceinline__ short f2bf(float f){
  __hip_bfloat16 b = __float2bfloat16(f);
  return __builtin_bit_cast(short, b);
}

// ---------------------------------------------------------------------------
// k_prep: (a) pack adj int32 -> bitmask words  (b) convert h, W fp32 -> bf16.
// BW-bound on the 134MB adj read (irreducible single pass).
// NOTE: keep pack + cvt in ONE low-VGPR kernel but do NOT fuse the GEMM here —
// R8 showed heterogeneous fusion raises VGPRs for the BW-bound blocks (+12us).
// ---------------------------------------------------------------------------
#define PACK_BLOCKS 1024
#define CVT_BLOCKS  1056
#define H_ELEMS (BN*IN)          // 2097152
__global__ __launch_bounds__(256) void k_prep(const int* __restrict__ adj,
                                              unsigned* __restrict__ bits,
                                              const float* __restrict__ hmat,
                                              const float* __restrict__ Wmat,
                                              short* __restrict__ hbf,
                                              short* __restrict__ wbf){
  if(blockIdx.x < PACK_BLOCKS){
    int t = blockIdx.x * 256 + threadIdx.x;          // [0, 262144)
    const int4* p = (const int4*)(adj + ((size_t)t << 5));
    unsigned word = 0;
    #pragma unroll
    for(int k = 0; k < 8; k++){
      int4 m = p[k];
      word |= (m.x != 0 ? 1u : 0u) << (k*4 + 0);
      word |= (m.y != 0 ? 1u : 0u) << (k*4 + 1);
      word |= (m.z != 0 ? 1u : 0u) << (k*4 + 2);
      word |= (m.w != 0 ? 1u : 0u) << (k*4 + 3);
    }
    bits[t] = word;
  } else {
    int idx = (blockIdx.x - PACK_BLOCKS) * 256 + threadIdx.x;  // [0, 270336)
    int e = idx * 8;
    const float* srcp; short* dstp;
    if(e < H_ELEMS){ srcp = hmat + e; dstp = hbf + e; }
    else           { srcp = Wmat + (e - H_ELEMS); dstp = wbf + (e - H_ELEMS); }
    float4 a0 = *(const float4*)srcp;
    float4 a1 = *(const float4*)(srcp + 4);
    short8 pk;
    pk[0]=f2bf(a0.x); pk[1]=f2bf(a0.y); pk[2]=f2bf(a0.z); pk[3]=f2bf(a0.w);
    pk[4]=f2bf(a1.x); pk[5]=f2bf(a1.y); pk[6]=f2bf(a1.z); pk[7]=f2bf(a1.w);
    *(short8*)dstp = pk;
  }
}

// ---------------------------------------------------------------------------
// k_wh: Wh = h @ W^T from pre-converted bf16; writes VT[b][h][d][n] (bf16) and
// fused src/dst epilogue (from fp32 acc).
// ---------------------------------------------------------------------------
__global__ __launch_bounds__(256) void k_wh(const short* __restrict__ hbf,
                                            const short* __restrict__ wbf,
                                            const float* __restrict__ avec,
                                            short* __restrict__ VT,
                                            float* __restrict__ src,
                                            float* __restrict__ dst){
  const int t = threadIdx.x;
  const int hh = t >> 6, lane = t & 63, quad = lane >> 4, l16 = lane & 15;
  const int mbase = blockIdx.x * 16;
  f32x4 acc[4];
  #pragma unroll
  for(int x=0;x<4;x++) acc[x] = (f32x4){0.f,0.f,0.f,0.f};
  const short* ap = hbf + (size_t)(mbase + l16) * IN + quad * 8;
  const short* bp0 = wbf + (size_t)(hh * 64 + l16) * IN + quad * 8;
  #pragma unroll
  for(int kk = 0; kk < 8; kk++){
    const int k0 = kk * 32;
    short8 A = *(const short8*)(ap + k0);
    #pragma unroll
    for(int dt=0; dt<4; dt++){
      short8 Bf = *(const short8*)(bp0 + (size_t)dt*16*IN + k0);
      acc[dt] = __builtin_amdgcn_mfma_f32_16x16x32_bf16(A, Bf, acc[dt], 0, 0, 0);
    }
  }
  const int bb = mbase >> 10;
  const int nb = (mbase & (N-1)) + quad * 4;
  const int bh = bb * H + hh;
  #pragma unroll
  for(int dt=0; dt<4; dt++){
    int d = dt*16 + l16;
    short4v pk;
    pk[0]=f2bf(acc[dt][0]); pk[1]=f2bf(acc[dt][1]);
    pk[2]=f2bf(acc[dt][2]); pk[3]=f2bf(acc[dt][3]);
    *(short4v*)(VT + (((size_t)bh * D + d) << 10) + nb) = pk;
  }
  float as[4], ad[4];
  #pragma unroll
  for(int dt=0; dt<4; dt++){
    as[dt] = avec[hh*(2*D) + dt*16 + l16];
    ad[dt] = avec[hh*(2*D) + D + dt*16 + l16];
  }
  #pragma unroll
  for(int r=0; r<4; r++){
    float s = 0.f, dd = 0.f;
    #pragma unroll
    for(int dt=0; dt<4; dt++){ s += acc[dt][r]*as[dt]; dd += acc[dt][r]*ad[dt]; }
    #pragma unroll
    for(int off=1; off<16; off<<=1){
      s  += __shfl_xor(s, off, 64);
      dd += __shfl_xor(dd, off, 64);
    }
    if(l16 == 0){
      int n = nb + r;
      src[(size_t)bh * N + n] = s;
      dst[(size_t)bh * N + n] = dd;
    }
  }
}

// ---------------------------------------------------------------------------
// k_attn: full-j masked-softmax + PV, software-pipelined (depth 2) B-fragment
// prefetch from global VT. Row-sums accumulated by an extra MFMA against a
// ones-fragment (no shuffle reduction, no VALU lsum chain).
// grid dim3(16, H, B) x 256; one barrier total.
// ---------------------------------------------------------------------------
__global__ __launch_bounds__(256, 4) void k_attn(const short* __restrict__ VT,
                                              const float* __restrict__ src,
                                              const float* __restrict__ dst,
                                              const unsigned* __restrict__ bits,
                                              float* __restrict__ out){
  __shared__ float dsh[N];
  const int t = threadIdx.x;
  const int wave = t >> 6, lane = t & 63, quad = lane >> 4, l16 = lane & 15;
  const int b = blockIdx.z, hh = blockIdx.y;
  const int bh = b * H + hh;
  const int i0 = blockIdx.x * 64;
  #pragma unroll
  for(int j = t; j < N; j += 256) dsh[j] = dst[(size_t)bh * N + j];
  const int i = i0 + wave * 16 + l16;
  const float si = src[(size_t)bh * N + i];
  // preload this row's full 1024 mask bits (32 words, 8 x int4)
  const int4* mp = (const int4*)(bits + ((size_t)b * N + i) * 32);
  int4 mv[8];
  #pragma unroll
  for(int k=0;k<8;k++) mv[k] = mp[k];
  const unsigned* mw = (const unsigned*)mv;
  const short* vrow = VT + (((size_t)bh * D) << 10) + quad * 8;
  // ones B-fragment (bf16 1.0 = 0x3F80) for row-sum accumulation
  short8 ones;
  #pragma unroll
  for(int k=0;k<8;k++) ones[k] = (short)0x3F80;
  f32x4 acc[4], accl;
  #pragma unroll
  for(int x=0;x<4;x++) acc[x] = (f32x4){0.f,0.f,0.f,0.f};
  accl = (f32x4){0.f,0.f,0.f,0.f};
  // 3 rotating register buffers for B-fragments (depth-2 prefetch)
  short8 buf[3][4];
  #pragma unroll
  for(int pre=0; pre<2; pre++)
    #pragma unroll
    for(int dt=0; dt<4; dt++)
      buf[pre][dt] = *(const short8*)(vrow + (((size_t)(dt*16 + l16)) << 10) + pre*32);
  __syncthreads();
  #pragma unroll
  for(int jt = 0; jt < 32; jt++){
    const int cur = jt % 3, nxt = (jt + 2) % 3;
    if(jt + 2 < 32){
      #pragma unroll
      for(int dt=0; dt<4; dt++)
        buf[nxt][dt] = *(const short8*)(vrow + (((size_t)(dt*16 + l16)) << 10) + (jt+2)*32);
    }
    const int j0 = jt * 32;
    const unsigned word = mw[jt];
    float4 d0 = *(const float4*)&dsh[j0 + quad*8];
    float4 d1 = *(const float4*)&dsh[j0 + quad*8 + 4];
    float dv[8] = {d0.x,d0.y,d0.z,d0.w,d1.x,d1.y,d1.z,d1.w};
    short8 P;
    #pragma unroll
    for(int jj=0; jj<8; jj++){
      float e = si + dv[jj];
      e = fmaxf(e, 0.2f * e);                          // leaky_relu(0.2)
      float p = ((word >> (quad*8 + jj)) & 1u) ? __expf(e) : 0.f;
      P[jj] = f2bf(p);
    }
    accl = __builtin_amdgcn_mfma_f32_16x16x32_bf16(P, ones, accl, 0, 0, 0);
    #pragma unroll
    for(int dt=0; dt<4; dt++)
      acc[dt] = __builtin_amdgcn_mfma_f32_16x16x32_bf16(P, buf[cur][dt], acc[dt], 0, 0, 0);
  }
  // epilogue: C row = quad*4+r, col = l16. accl[r] holds that row's sum
  // (identical across cols) -> denominator is already lane-local.
  #pragma unroll
  for(int r=0; r<4; r++){
    float inv = 1.0f / accl[r];
    int ig = i0 + wave*16 + quad*4 + r;
    float* op = out + ((size_t)b * N + ig) * O + hh * D + l16;
    #pragma unroll
    for(int dt=0; dt<4; dt++) op[dt*16] = acc[dt][r] * inv;
  }
}

extern "C" void kernel_launch(void* const* d_in, const int* in_sizes, int n_in,
                              void* d_out, int out_size, void* d_ws, size_t ws_size,
                              hipStream_t stream) {
  const float* hmat = (const float*)d_in[0];
  const float* Wmat = (const float*)d_in[1];
  const float* avec = (const float*)d_in[2];
  const int* adj    = (const int*)d_in[3];   // numpy bool -> int32 per harness
  float* out = (float*)d_out;
  char* ws = (char*)d_ws;
  short*    VT    = (short*)   (ws);                         //  4 MB
  short*    hbf   = (short*)   (ws + (size_t) 4*1024*1024);  //  4 MB
  short*    wbf   = (short*)   (ws + (size_t) 8*1024*1024);  //  128 KB
  unsigned* bits  = (unsigned*)(ws + (size_t) 9*1024*1024);  //  1 MB
  float*    src   = (float*)   (ws + (size_t)10*1024*1024);  //  128 KB
  float*    dst   = (float*)   (ws + (size_t)10*1024*1024 + 131072);
  k_prep<<<PACK_BLOCKS + CVT_BLOCKS, 256, 0, stream>>>(adj, bits, hmat, Wmat, hbf, wbf);
  k_wh<<<BN/16, 256, 0, stream>>>(hbf, wbf, avec, VT, src, dst);
  k_attn<<<dim3(16, H, B), 256, 0, stream>>>(VT, src, dst, bits, out);
}